// Round 8
// baseline (343.450 us; speedup 1.0000x reference)
//
#include <hip/hip_runtime.h>
#include <hip/hip_bf16.h>
#include <hip/hip_fp16.h>

// Problem constants (match reference)
static constexpr int CH     = 128;   // IN_CH == HID
static constexpr int NCLS   = 32;
static constexpr int NGRAPH = 256;

// Bucketed CSR build: buckets are 256-node ranges (bucket = dst >> 8).
static constexpr int BSHIFT = 8;
static constexpr int BW     = 1 << BSHIFT;   // 256 nodes per bucket
static constexpr int MAXB   = 512;

typedef _Float16 half8 __attribute__((ext_vector_type(8)));
typedef _Float16 half4 __attribute__((ext_vector_type(4)));
typedef float    f32x4 __attribute__((ext_vector_type(4)));
typedef float    f32x2 __attribute__((ext_vector_type(2)));

// fp8 (OCP e4m3) gather buffer, row-major [N+1][128] (row N = zero pad row).
static constexpr float FP8_SCALE = 64.0f;
static constexpr float FP8_INV   = 1.0f / 64.0f;

__device__ __forceinline__ unsigned char enc8(float v) {
  return (unsigned char)(__builtin_amdgcn_cvt_pk_fp8_f32(v, v, 0, false) & 0xFF);
}

// ---------------------------------------------------------------------------
// 1) scatter packed edges into over-allocated bucket regions.
//    pack = (dstlo << 17) | src. Block-local LDS bucket sort, then coalesced
//    copy-out. (R7 version, unchanged -- control for this diagnostic round.)
// ---------------------------------------------------------------------------
__global__ __launch_bounds__(1024) void k_scatter(
    const int* __restrict__ src, const int* __restrict__ dst,
    int* __restrict__ gcur, int* __restrict__ ebuf, int E, int CAP,
    int* __restrict__ xzero) {
  __shared__ int bcnt[MAXB];               // 2KB
  __shared__ int lofs[MAXB];               // 2KB (inclusive scan)
  __shared__ int bbase[MAXB];              // 2KB
  __shared__ int sorted[8192];             // 32KB
  __shared__ unsigned short sbkt[8192];    // 16KB
  int t = threadIdx.x;
  if (blockIdx.x == 0 && t < 32) xzero[t] = 0;   // 128B fp8 zero row
  if (t < MAXB) bcnt[t] = 0;
  __syncthreads();
  int base = blockIdx.x * 8192;
  int cnt = E - base; if (cnt > 8192) cnt = 8192;
  int p_[8], b_[8], r_[8];
  #pragma unroll
  for (int j = 0; j < 8; ++j) {
    int i = j * 1024 + t;
    if (i < cnt) {
      int s = src[base + i], d = dst[base + i];
      b_[j] = d >> BSHIFT;
      p_[j] = ((d & (BW - 1)) << 17) | s;
      r_[j] = atomicAdd(&bcnt[b_[j]], 1);
    }
  }
  __syncthreads();
  if (t < MAXB) lofs[t] = bcnt[t];
  __syncthreads();
  for (int st = 1; st < MAXB; st <<= 1) {
    int v = (t < MAXB && t >= st) ? lofs[t - st] : 0;
    __syncthreads();
    if (t < MAXB) lofs[t] += v;
    __syncthreads();
  }
  if (t < MAXB && bcnt[t]) bbase[t] = atomicAdd(&gcur[t], bcnt[t]);
  __syncthreads();
  #pragma unroll
  for (int j = 0; j < 8; ++j) {
    int i = j * 1024 + t;
    if (i < cnt) {
      int pos = lofs[b_[j]] - bcnt[b_[j]] + r_[j];   // exclusive start + rank
      sorted[pos] = p_[j];
      sbkt[pos] = (unsigned short)b_[j];
    }
  }
  __syncthreads();
  for (int i = t; i < cnt; i += 1024) {
    int bk = sbkt[i];
    ebuf[bk * CAP + bbase[bk] + (i - (lofs[bk] - bcnt[bk]))] = sorted[i];
  }
}

// ---------------------------------------------------------------------------
// 2) per-bucket CSR build. Histogram + scan, then chunked LDS node-sort with
//    coalesced copy-out. Blocks 0..31 fold in the W1/W2 fp16 transpose.
//    (R7 version, unchanged -- control.)
// ---------------------------------------------------------------------------
__global__ __launch_bounds__(1024) void k_build(
    const int* __restrict__ ebuf, const int* __restrict__ gcur,
    int* __restrict__ offs, int* __restrict__ oend,
    float* __restrict__ dinv, int* __restrict__ csr, int N, int CAP,
    const float* __restrict__ W1, const float* __restrict__ W2,
    _Float16* __restrict__ WhT1, _Float16* __restrict__ WhT2) {
  __shared__ int sdeg[BW];                 // 1KB
  __shared__ int sscan[BW];                // 1KB
  __shared__ int cur[BW];                  // 1KB
  __shared__ int chist[BW];                // 1KB
  __shared__ int clofs[BW];                // 1KB
  __shared__ int lsorted[8192];            // 32KB
  __shared__ unsigned char lnode[8192];    // 8KB
  int b = blockIdx.x;
  int t = threadIdx.x;

  // folded weight transpose (2*128*128 elements over blocks 0..31)
  int gi = b * 1024 + t;
  if (gi < 2 * CH * CH) {
    const float* W = (gi < CH * CH) ? W1 : W2;
    _Float16* T   = (gi < CH * CH) ? WhT1 : WhT2;
    int j = gi & (CH * CH - 1);
    int k = j >> 7, n = j & 127;
    T[n * CH + k] = (_Float16)W[j];
  }

  int lo = b << BSHIFT;
  int e0 = b * CAP;
  int CNT = gcur[b];

  if (t < BW) sdeg[t] = 0;
  __syncthreads();
  for (int i = t; i < CNT; i += 1024)
    atomicAdd(&sdeg[ebuf[e0 + i] >> 17], 1);
  __syncthreads();
  if (t < BW) sscan[t] = (sdeg[t] + 3) & ~3;     // padded degree
  __syncthreads();
  for (int st = 1; st < BW; st <<= 1) {
    int v = (t < BW && t >= st) ? sscan[t - st] : 0;
    __syncthreads();
    if (t < BW) sscan[t] += v;
    __syncthreads();
  }
  if (t < BW) {
    int deg  = sdeg[t];
    int pdeg = (deg + 3) & ~3;
    int ex = b * CAP + sscan[t] - pdeg;          // 4-aligned (CAP%4==0)
    int n = lo + t;
    if (n < N) {
      offs[n] = ex;
      oend[n] = ex + deg;
      dinv[n] = 1.0f / sqrtf((float)(deg + 1));
      for (int q = deg; q < pdeg; ++q) csr[ex + q] = N;   // zero-row pad
      cur[t] = ex;
    }
  }
  __syncthreads();

  // chunked sorted fill
  for (int c0 = 0; c0 < CNT; c0 += 8192) {
    int ccnt = CNT - c0; if (ccnt > 8192) ccnt = 8192;
    if (t < BW) chist[t] = 0;
    __syncthreads();
    int p_[8], nd_[8], r_[8];
    #pragma unroll
    for (int j = 0; j < 8; ++j) {
      int i = j * 1024 + t;
      if (i < ccnt) {
        p_[j] = ebuf[e0 + c0 + i];
        nd_[j] = p_[j] >> 17;
        r_[j] = atomicAdd(&chist[nd_[j]], 1);
      }
    }
    __syncthreads();
    if (t < BW) clofs[t] = chist[t];
    __syncthreads();
    for (int st = 1; st < BW; st <<= 1) {
      int v = (t < BW && t >= st) ? clofs[t - st] : 0;
      __syncthreads();
      if (t < BW) clofs[t] += v;
      __syncthreads();
    }
    #pragma unroll
    for (int j = 0; j < 8; ++j) {
      int i = j * 1024 + t;
      if (i < ccnt) {
        int pos = clofs[nd_[j]] - chist[nd_[j]] + r_[j];
        lsorted[pos] = p_[j];
        lnode[pos] = (unsigned char)nd_[j];
      }
    }
    __syncthreads();
    for (int i = t; i < ccnt; i += 1024) {
      int nd = lnode[i];
      int gpos = cur[nd] + (i - (clofs[nd] - chist[nd]));
      csr[gpos] = lsorted[i] & 0x1FFFF;
    }
    __syncthreads();
    if (t < BW) cur[t] += chist[t];
    __syncthreads();
  }
}

// ---------------------------------------------------------------------------
// waveGemm: Ws staged ONCE per block, each wave grid-strides 16-row tiles,
// A-fragments global->register, no per-tile barriers. (R7, unchanged.)
// ---------------------------------------------------------------------------
__device__ __forceinline__ void stage_w(const _Float16* __restrict__ WhT,
                                        _Float16 (*Ws)[136], int tid) {
  #pragma unroll
  for (int l = 0; l < 8; ++l) {
    int idx = tid + l * 256;            // 0..2047 half8 chunks
    int n = idx >> 4, k8 = (idx & 15) << 3;
    *(half8*)&Ws[n][k8] = *(const half8*)(WhT + n * CH + k8);
  }
}

__device__ __forceinline__ void gemm_tile(
    const _Float16 (*Ws)[136], const half8* af,
    const float* __restrict__ dinv, unsigned char* __restrict__ C,
    int tile, int M, int quad, int sub) {
  f32x4 acc[8];
  #pragma unroll
  for (int j = 0; j < 8; ++j) acc[j] = (f32x4){0.f, 0.f, 0.f, 0.f};
  #pragma unroll
  for (int kc = 0; kc < 4; ++kc) {
    #pragma unroll
    for (int nt = 0; nt < 8; ++nt) {
      half8 b = *(const half8*)&Ws[nt * 16 + sub][kc * 32 + quad * 8];
      acc[nt] = __builtin_amdgcn_mfma_f32_16x16x32_f16(af[kc], b, acc[nt], 0, 0, 0);
    }
  }
  #pragma unroll
  for (int r = 0; r < 4; ++r) {
    int orow = tile * 16 + quad * 4 + r;
    if (orow < M) {
      float d = dinv[orow] * FP8_SCALE;
      #pragma unroll
      for (int nt = 0; nt < 8; ++nt)
        C[(size_t)orow * CH + nt * 16 + sub] = enc8(acc[nt][r] * d);
    }
  }
}

// A input fp32 (layer 1: x)
__global__ __launch_bounds__(256) void k_gemm_f32(
    const float* __restrict__ A, const _Float16* __restrict__ WhT,
    const float* __restrict__ dinv, unsigned char* __restrict__ C, int M) {
  __shared__ _Float16 Ws[128][136];
  int tid = threadIdx.x;
  stage_w(WhT, Ws, tid);
  __syncthreads();
  int lane = tid & 63;
  int quad = lane >> 4, sub = lane & 15;
  int ntiles = (M + 15) >> 4;
  int wid0 = blockIdx.x * 4 + (tid >> 6);
  int wstep = gridDim.x * 4;
  for (int tile = wid0; tile < ntiles; tile += wstep) {
    int row = tile * 16 + sub; if (row >= M) row = M - 1;
    const float* arow = A + (size_t)row * CH + quad * 8;
    half8 af[4];
    #pragma unroll
    for (int kc = 0; kc < 4; ++kc) {
      float4 v0 = *(const float4*)(arow + kc * 32);
      float4 v1 = *(const float4*)(arow + kc * 32 + 4);
      af[kc] = (half8){(_Float16)v0.x, (_Float16)v0.y, (_Float16)v0.z, (_Float16)v0.w,
                       (_Float16)v1.x, (_Float16)v1.y, (_Float16)v1.z, (_Float16)v1.w};
    }
    gemm_tile(Ws, af, dinv, C, tile, M, quad, sub);
  }
}

// A input fp16 (layer 2: h)
__global__ __launch_bounds__(256) void k_gemm_f16(
    const _Float16* __restrict__ A, const _Float16* __restrict__ WhT,
    const float* __restrict__ dinv, unsigned char* __restrict__ C, int M) {
  __shared__ _Float16 Ws[128][136];
  int tid = threadIdx.x;
  stage_w(WhT, Ws, tid);
  __syncthreads();
  int lane = tid & 63;
  int quad = lane >> 4, sub = lane & 15;
  int ntiles = (M + 15) >> 4;
  int wid0 = blockIdx.x * 4 + (tid >> 6);
  int wstep = gridDim.x * 4;
  for (int tile = wid0; tile < ntiles; tile += wstep) {
    int row = tile * 16 + sub; if (row >= M) row = M - 1;
    const _Float16* arow = A + (size_t)row * CH + quad * 8;
    half8 af[4];
    #pragma unroll
    for (int kc = 0; kc < 4; ++kc)
      af[kc] = *(const half8*)(arow + kc * 32);
    gemm_tile(Ws, af, dinv, C, tile, M, quad, sub);
  }
}

// ---------------------------------------------------------------------------
// Aggregation (pull, CSR): R6/R7 structure, now parameterized by node range
// [nLo, nHi) so each layer runs as TWO half-range dispatches (~30 us each).
// DIAGNOSTIC: agg no longer monopolizes the top-5 dispatch table, exposing
// the hidden scatter/build/gemm/poolfc counters. nLo must be even.
// ---------------------------------------------------------------------------
__global__ __launch_bounds__(256) void k_agg(
    const unsigned int* __restrict__ xs32, const int* __restrict__ csr,
    const int* __restrict__ offs, const int* __restrict__ oend,
    const float* __restrict__ dinv, const float* __restrict__ bias,
    __half* __restrict__ out, int nLo, int nHi) {
  int lane  = threadIdx.x & 63;
  int wid0  = blockIdx.x * 4 + (threadIdx.x >> 6);
  int wstep = gridDim.x * 4;
  int e = lane >> 5;                    // edge slot within pair
  unsigned int c = lane & 31;           // dword index within row
  float4 bb = *(const float4*)(bias + c * 4);

  auto G = [&](int s) -> unsigned int {
    return xs32[((unsigned int)s << 5) | c];
  };

  for (int wid = wid0 + (nLo >> 1); wid * 2 < nHi; wid += wstep) {
    int nA = wid * 2, nB = nA + 1;
    bool hasB = (nB < nHi);

    int eA = offs[nA];
    int cA = (oend[nA] - eA + 3) >> 2;                 // int4 chunk count
    int eB = hasB ? offs[nB] : eA;
    int cB = hasB ? ((oend[nB] - eB + 3) >> 2) : 0;

    f32x2 a0 = {0.f, 0.f}, a1 = {0.f, 0.f};
    f32x2 b0 = {0.f, 0.f}, b1 = {0.f, 0.f};
    if (e == 0) {                        // self row, counted once
      unsigned int ow = G(nA);
      a0 = __builtin_amdgcn_cvt_pk_f32_fp8((int)ow, false);
      a1 = __builtin_amdgcn_cvt_pk_f32_fp8((int)ow, true);
      if (hasB) {
        unsigned int ob = G(nB);
        b0 = __builtin_amdgcn_cvt_pk_f32_fp8((int)ob, false);
        b1 = __builtin_amdgcn_cvt_pk_f32_fp8((int)ob, true);
      }
    }

    #define ACC(d, x0, x1) \
      x0 += __builtin_amdgcn_cvt_pk_f32_fp8((int)(d), false); \
      x1 += __builtin_amdgcn_cvt_pk_f32_fp8((int)(d), true);

    if (cA >= 2 && cB >= 2) {
      int4 ca0 = *(const int4*)(csr + eA);
      int4 ca1 = *(const int4*)(csr + eA + 4);
      int4 cb0 = *(const int4*)(csr + eB);
      int4 cb1 = *(const int4*)(csr + eB + 4);
      do {
        int sA0 = e ? ca0.y : ca0.x, sA1 = e ? ca0.w : ca0.z;
        int sA2 = e ? ca1.y : ca1.x, sA3 = e ? ca1.w : ca1.z;
        int sB0 = e ? cb0.y : cb0.x, sB1 = e ? cb0.w : cb0.z;
        int sB2 = e ? cb1.y : cb1.x, sB3 = e ? cb1.w : cb1.z;
        unsigned int dA0 = G(sA0), dA1 = G(sA1), dA2 = G(sA2), dA3 = G(sA3);
        unsigned int dB0 = G(sB0), dB1 = G(sB1), dB2 = G(sB2), dB3 = G(sB3);
        eA += 8; eB += 8; cA -= 2; cB -= 2;
        int4 na0 = *(const int4*)(csr + eA);
        int4 na1 = *(const int4*)(csr + eA + 4);
        int4 nb0 = *(const int4*)(csr + eB);
        int4 nb1 = *(const int4*)(csr + eB + 4);
        ACC(dA0, a0, a1); ACC(dA1, a0, a1); ACC(dA2, a0, a1); ACC(dA3, a0, a1);
        ACC(dB0, b0, b1); ACC(dB1, b0, b1); ACC(dB2, b0, b1); ACC(dB3, b0, b1);
        ca0 = na0; ca1 = na1; cb0 = nb0; cb1 = nb1;
      } while (cA >= 2 && cB >= 2);
    }

    auto drain = [&](int ee, int cc, f32x2& x0, f32x2& x1) {
      while (cc >= 2) {
        int4 q0 = *(const int4*)(csr + ee);
        int4 q1 = *(const int4*)(csr + ee + 4);
        int s0 = e ? q0.y : q0.x, s1 = e ? q0.w : q0.z;
        int s2 = e ? q1.y : q1.x, s3 = e ? q1.w : q1.z;
        unsigned int d0 = G(s0), d1 = G(s1), d2 = G(s2), d3 = G(s3);
        ACC(d0, x0, x1); ACC(d1, x0, x1); ACC(d2, x0, x1); ACC(d3, x0, x1);
        ee += 8; cc -= 2;
      }
      if (cc > 0) {
        int4 q0 = *(const int4*)(csr + ee);
        int s0 = e ? q0.y : q0.x, s1 = e ? q0.w : q0.z;
        unsigned int d0 = G(s0), d1 = G(s1);
        ACC(d0, x0, x1); ACC(d1, x0, x1);
      }
    };
    drain(eA, cA, a0, a1);
    if (hasB) drain(eB, cB, b0, b1);
    #undef ACC

    a0[0] += __shfl_xor(a0[0], 32); a0[1] += __shfl_xor(a0[1], 32);
    a1[0] += __shfl_xor(a1[0], 32); a1[1] += __shfl_xor(a1[1], 32);
    if (hasB) {
      b0[0] += __shfl_xor(b0[0], 32); b0[1] += __shfl_xor(b0[1], 32);
      b1[0] += __shfl_xor(b1[0], 32); b1[1] += __shfl_xor(b1[1], 32);
    }

    if (e == 0) {
      {
        float dn = dinv[nA] * FP8_INV;
        float r0 = fmaf(a0[0], dn, bb.x), r1 = fmaf(a0[1], dn, bb.y);
        float r2 = fmaf(a1[0], dn, bb.z), r3 = fmaf(a1[1], dn, bb.w);
        __half2 h0 = __floats2half2_rn(fmaxf(r0, 0.f), fmaxf(r1, 0.f));
        __half2 h1 = __floats2half2_rn(fmaxf(r2, 0.f), fmaxf(r3, 0.f));
        __half2* op = (__half2*)(out + (size_t)nA * CH + c * 4);
        op[0] = h0; op[1] = h1;
      }
      if (hasB) {
        float dn = dinv[nB] * FP8_INV;
        float r0 = fmaf(b0[0], dn, bb.x), r1 = fmaf(b0[1], dn, bb.y);
        float r2 = fmaf(b1[0], dn, bb.z), r3 = fmaf(b1[1], dn, bb.w);
        __half2 h0 = __floats2half2_rn(fmaxf(r0, 0.f), fmaxf(r1, 0.f));
        __half2 h1 = __floats2half2_rn(fmaxf(r2, 0.f), fmaxf(r3, 0.f));
        __half2* op = (__half2*)(out + (size_t)nB * CH + c * 4);
        op[0] = h0; op[1] = h1;
      }
    }
  }
}

// ---------------------------------------------------------------------------
// Fused pool + FC: one block per graph, binary-search boundaries. (R6/R7.)
// ---------------------------------------------------------------------------
__global__ __launch_bounds__(256) void k_poolfc(
    const __half* __restrict__ h, const int* __restrict__ batch,
    const float* __restrict__ Wfc, const float* __restrict__ bfc,
    float* __restrict__ outp, int N) {
  __shared__ float sred[256][2];
  __shared__ float gs[CH];
  int g = blockIdx.x;
  int t = threadIdx.x;

  int lo = 0, hi = N;
  while (lo < hi) { int m = (lo + hi) >> 1; if (batch[m] < g) lo = m + 1; else hi = m; }
  int s0 = lo;
  hi = N;
  while (lo < hi) { int m = (lo + hi) >> 1; if (batch[m] < g + 1) lo = m + 1; else hi = m; }
  int s1 = lo;

  int ch2 = t & 63;
  int rh  = t >> 6;
  const __half2* h2 = (const __half2*)h;
  float ax = 0.f, ay = 0.f;
  for (int n = s0 + rh; n < s1; n += 4) {
    float2 v = __half22float2(h2[(size_t)n * 64 + ch2]);
    ax += v.x; ay += v.y;
  }
  sred[t][0] = ax; sred[t][1] = ay;
  __syncthreads();
  if (t < 64) {
    float invc = 1.0f / fmaxf((float)(s1 - s0), 1.0f);
    float sx = sred[t][0] + sred[t + 64][0] + sred[t + 128][0] + sred[t + 192][0];
    float sy = sred[t][1] + sred[t + 64][1] + sred[t + 128][1] + sred[t + 192][1];
    gs[2 * t]     = sx * invc;
    gs[2 * t + 1] = sy * invc;
  }
  __syncthreads();
  if (t < NCLS) {
    float acc = bfc[t];
    #pragma unroll 8
    for (int cc = 0; cc < CH; ++cc)
      acc = fmaf(gs[cc], Wfc[cc * NCLS + t], acc);
    outp[g * NCLS + t] = acc;
  }
}

// ---------------------------------------------------------------------------
extern "C" void kernel_launch(void* const* d_in, const int* in_sizes, int n_in,
                              void* d_out, int out_size, void* d_ws, size_t ws_size,
                              hipStream_t stream) {
  const float* x    = (const float*)d_in[0];
  const int*   ei   = (const int*)d_in[1];
  const int*   batch= (const int*)d_in[2];
  const float* W1   = (const float*)d_in[3];
  const float* b1   = (const float*)d_in[4];
  const float* W2   = (const float*)d_in[5];
  const float* b2   = (const float*)d_in[6];
  const float* Wfc  = (const float*)d_in[7];
  const float* bfc  = (const float*)d_in[8];
  float* outp = (float*)d_out;

  const int N = in_sizes[0] / CH;       // 100000
  const int E = in_sizes[1] / 2;        // 3200000
  const int* src = ei;
  const int* dst = ei + E;
  const int NBUCK = (N + BW - 1) >> BSHIFT;   // 391
  int CAP = (E / NBUCK) + (E / NBUCK) / 8 + 1280;
  CAP = (CAP + 3) & ~3;                       // keep per-bucket base 4-aligned

  // Workspace carve (256B aligned).
  char* w = (char*)d_ws;
  size_t o = 0;
  auto carve = [&](size_t bytes) -> void* {
    o = (o + 255) & ~(size_t)255;
    void* p = w + o;
    o += bytes;
    return p;
  };
  int*      offs   = (int*)     carve((size_t)N * 4);
  int*      oendb  = (int*)     carve((size_t)N * 4);
  int*      gcur   = (int*)     carve(MAXB * 4);                 // zeroed
  int*      csr    = (int*)     carve((size_t)NBUCK * CAP * 4);
  float*    dinv   = (float*)   carve((size_t)N * 4);
  _Float16* WhT1   = (_Float16*)carve((size_t)CH * CH * 2);
  _Float16* WhT2   = (_Float16*)carve((size_t)CH * CH * 2);
  unsigned char* xsbuf = (unsigned char*)carve((size_t)(N + 1) * CH); // fp8 + zero row
  __half*   hbuf   = (__half*)  carve((size_t)N * CH * 2);            // fp16 h
  (void)ws_size;

  // ebuf (packed edges, gapped) aliases hbuf: NBUCK*CAP*4 ~ 16.4MB <= 25.6MB
  int* ebuf = (int*)hbuf;

  (void)hipMemsetAsync(gcur, 0, MAXB * 4, stream);

  const int GBW = 1024;                 // waveGemm blocks (4/CU)
  const int NHALF = (N / 2) & ~1;       // 50000, even
  int AB = (N / 2 + 7) / 8;
  if (AB > 2048) AB = 2048;

  k_scatter<<<(E + 8191) / 8192, 1024, 0, stream>>>(
      src, dst, gcur, ebuf, E, CAP, (int*)(xsbuf + (size_t)N * CH));
  k_build<<<NBUCK, 1024, 0, stream>>>(ebuf, gcur, offs, oendb, dinv, csr,
                                      N, CAP, W1, W2, WhT1, WhT2);

  // Layer 1: xs = fp8((x@W1)*dinv*64) ; h = fp16(relu(agg(xs)*dinv/64 + b1))
  k_gemm_f32<<<GBW, 256, 0, stream>>>(x, WhT1, dinv, xsbuf, N);
  k_agg<<<AB, 256, 0, stream>>>((const unsigned int*)xsbuf, csr, offs, oendb,
                                dinv, b1, hbuf, 0, NHALF);
  k_agg<<<AB, 256, 0, stream>>>((const unsigned int*)xsbuf, csr, offs, oendb,
                                dinv, b1, hbuf, NHALF, N);
  // Layer 2
  k_gemm_f16<<<GBW, 256, 0, stream>>>((const _Float16*)hbuf, WhT2, dinv, xsbuf, N);
  k_agg<<<AB, 256, 0, stream>>>((const unsigned int*)xsbuf, csr, offs, oendb,
                                dinv, b2, hbuf, 0, NHALF);
  k_agg<<<AB, 256, 0, stream>>>((const unsigned int*)xsbuf, csr, offs, oendb,
                                dinv, b2, hbuf, NHALF, N);

  // Fused pool + FC
  k_poolfc<<<NGRAPH, 256, 0, stream>>>(hbuf, batch, Wfc, bfc, outp, N);
  (void)out_size; (void)n_in;
}

// Round 9
// 300.562 us; speedup vs baseline: 1.1427x; 1.1427x over previous
//
#include <hip/hip_runtime.h>
#include <hip/hip_bf16.h>
#include <hip/hip_fp16.h>

// Problem constants (match reference)
static constexpr int CH     = 128;   // IN_CH == HID
static constexpr int NCLS   = 32;
static constexpr int NGRAPH = 256;

// Bucketed CSR build: buckets are 256-node ranges (bucket = dst >> 8).
static constexpr int BSHIFT = 8;
static constexpr int BW     = 1 << BSHIFT;   // 256 nodes per bucket
static constexpr int MAXB   = 512;

typedef _Float16 half8 __attribute__((ext_vector_type(8)));
typedef _Float16 half4 __attribute__((ext_vector_type(4)));
typedef float    f32x4 __attribute__((ext_vector_type(4)));
typedef float    f32x2 __attribute__((ext_vector_type(2)));

// fp8 (OCP e4m3) gather buffer, row-major [N+1][128] (row N = zero pad row).
static constexpr float FP8_SCALE = 64.0f;
static constexpr float FP8_INV   = 1.0f / 64.0f;

__device__ __forceinline__ unsigned char enc8(float v) {
  return (unsigned char)(__builtin_amdgcn_cvt_pk_fp8_f32(v, v, 0, false) & 0xFF);
}

// ---------------------------------------------------------------------------
// 1) scatter packed edges into over-allocated bucket regions (LDS bucket
//    sort + coalesced copy-out). Side jobs: zero fp8 pad row (block 0) and
//    graph-boundary detection (first N threads write gstart/gend directly,
//    so k_fc needs no binary search).
// ---------------------------------------------------------------------------
__global__ __launch_bounds__(1024) void k_scatter(
    const int* __restrict__ src, const int* __restrict__ dst,
    int* __restrict__ gcur, int* __restrict__ ebuf, int E, int CAP,
    int* __restrict__ xzero, const int* __restrict__ batch,
    int* __restrict__ gstart, int* __restrict__ gend, int Nn) {
  __shared__ int bcnt[MAXB];               // 2KB
  __shared__ int lofs[MAXB];               // 2KB (inclusive scan)
  __shared__ int bbase[MAXB];              // 2KB
  __shared__ int sorted[8192];             // 32KB
  __shared__ unsigned short sbkt[8192];    // 16KB
  int t = threadIdx.x;
  if (blockIdx.x == 0 && t < 32) xzero[t] = 0;   // 128B fp8 zero row
  {  // graph boundaries (batch sorted): direct writes, no search later
    int i = blockIdx.x * 1024 + t;
    if (i < Nn) {
      int bg = batch[i];
      if (i == 0 || batch[i - 1] != bg) gstart[bg] = i;
      if (i == Nn - 1 || batch[i + 1] != bg) gend[bg] = i + 1;
    }
  }
  if (t < MAXB) bcnt[t] = 0;
  __syncthreads();
  int base = blockIdx.x * 8192;
  int cnt = E - base; if (cnt > 8192) cnt = 8192;
  int p_[8], b_[8], r_[8];
  #pragma unroll
  for (int j = 0; j < 8; ++j) {
    int i = j * 1024 + t;
    if (i < cnt) {
      int s = src[base + i], d = dst[base + i];
      b_[j] = d >> BSHIFT;
      p_[j] = ((d & (BW - 1)) << 17) | s;
      r_[j] = atomicAdd(&bcnt[b_[j]], 1);
    }
  }
  __syncthreads();
  if (t < MAXB) lofs[t] = bcnt[t];
  __syncthreads();
  for (int st = 1; st < MAXB; st <<= 1) {
    int v = (t < MAXB && t >= st) ? lofs[t - st] : 0;
    __syncthreads();
    if (t < MAXB) lofs[t] += v;
    __syncthreads();
  }
  if (t < MAXB && bcnt[t]) bbase[t] = atomicAdd(&gcur[t], bcnt[t]);
  __syncthreads();
  #pragma unroll
  for (int j = 0; j < 8; ++j) {
    int i = j * 1024 + t;
    if (i < cnt) {
      int pos = lofs[b_[j]] - bcnt[b_[j]] + r_[j];   // exclusive start + rank
      sorted[pos] = p_[j];
      sbkt[pos] = (unsigned short)b_[j];
    }
  }
  __syncthreads();
  for (int i = t; i < cnt; i += 1024) {
    int bk = sbkt[i];
    ebuf[bk * CAP + bbase[bk] + (i - (lofs[bk] - bcnt[bk]))] = sorted[i];
  }
}

// ---------------------------------------------------------------------------
// 2) per-bucket CSR build. Histogram + scan, then chunked LDS node-sort with
//    coalesced copy-out. Blocks 0..31 fold in the W1/W2 fp16 transpose.
// ---------------------------------------------------------------------------
__global__ __launch_bounds__(1024) void k_build(
    const int* __restrict__ ebuf, const int* __restrict__ gcur,
    int* __restrict__ offs, int* __restrict__ oend,
    float* __restrict__ dinv, int* __restrict__ csr, int N, int CAP,
    const float* __restrict__ W1, const float* __restrict__ W2,
    _Float16* __restrict__ WhT1, _Float16* __restrict__ WhT2) {
  __shared__ int sdeg[BW];                 // 1KB
  __shared__ int sscan[BW];                // 1KB
  __shared__ int cur[BW];                  // 1KB
  __shared__ int chist[BW];                // 1KB
  __shared__ int clofs[BW];                // 1KB
  __shared__ int lsorted[8192];            // 32KB
  __shared__ unsigned char lnode[8192];    // 8KB
  int b = blockIdx.x;
  int t = threadIdx.x;

  // folded weight transpose (2*128*128 elements over blocks 0..31)
  int gi = b * 1024 + t;
  if (gi < 2 * CH * CH) {
    const float* W = (gi < CH * CH) ? W1 : W2;
    _Float16* T   = (gi < CH * CH) ? WhT1 : WhT2;
    int j = gi & (CH * CH - 1);
    int k = j >> 7, n = j & 127;
    T[n * CH + k] = (_Float16)W[j];
  }

  int lo = b << BSHIFT;
  int e0 = b * CAP;
  int CNT = gcur[b];

  if (t < BW) sdeg[t] = 0;
  __syncthreads();
  for (int i = t; i < CNT; i += 1024)
    atomicAdd(&sdeg[ebuf[e0 + i] >> 17], 1);
  __syncthreads();
  if (t < BW) sscan[t] = (sdeg[t] + 3) & ~3;     // padded degree
  __syncthreads();
  for (int st = 1; st < BW; st <<= 1) {
    int v = (t < BW && t >= st) ? sscan[t - st] : 0;
    __syncthreads();
    if (t < BW) sscan[t] += v;
    __syncthreads();
  }
  if (t < BW) {
    int deg  = sdeg[t];
    int pdeg = (deg + 3) & ~3;
    int ex = b * CAP + sscan[t] - pdeg;          // 4-aligned (CAP%4==0)
    int n = lo + t;
    if (n < N) {
      offs[n] = ex;
      oend[n] = ex + deg;
      dinv[n] = 1.0f / sqrtf((float)(deg + 1));
      for (int q = deg; q < pdeg; ++q) csr[ex + q] = N;   // zero-row pad
      cur[t] = ex;
    }
  }
  __syncthreads();

  // chunked sorted fill
  for (int c0 = 0; c0 < CNT; c0 += 8192) {
    int ccnt = CNT - c0; if (ccnt > 8192) ccnt = 8192;
    if (t < BW) chist[t] = 0;
    __syncthreads();
    int p_[8], nd_[8], r_[8];
    #pragma unroll
    for (int j = 0; j < 8; ++j) {
      int i = j * 1024 + t;
      if (i < ccnt) {
        p_[j] = ebuf[e0 + c0 + i];
        nd_[j] = p_[j] >> 17;
        r_[j] = atomicAdd(&chist[nd_[j]], 1);
      }
    }
    __syncthreads();
    if (t < BW) clofs[t] = chist[t];
    __syncthreads();
    for (int st = 1; st < BW; st <<= 1) {
      int v = (t < BW && t >= st) ? clofs[t - st] : 0;
      __syncthreads();
      if (t < BW) clofs[t] += v;
      __syncthreads();
    }
    #pragma unroll
    for (int j = 0; j < 8; ++j) {
      int i = j * 1024 + t;
      if (i < ccnt) {
        int pos = clofs[nd_[j]] - chist[nd_[j]] + r_[j];
        lsorted[pos] = p_[j];
        lnode[pos] = (unsigned char)nd_[j];
      }
    }
    __syncthreads();
    for (int i = t; i < ccnt; i += 1024) {
      int nd = lnode[i];
      int gpos = cur[nd] + (i - (clofs[nd] - chist[nd]));
      csr[gpos] = lsorted[i] & 0x1FFFF;
    }
    __syncthreads();
    if (t < BW) cur[t] += chist[t];
    __syncthreads();
  }
}

// ---------------------------------------------------------------------------
// waveGemm: Ws staged ONCE per block, each wave grid-strides 16-row tiles,
// A-fragments global->register, no per-tile barriers.
// ---------------------------------------------------------------------------
__device__ __forceinline__ void stage_w(const _Float16* __restrict__ WhT,
                                        _Float16 (*Ws)[136], int tid) {
  #pragma unroll
  for (int l = 0; l < 8; ++l) {
    int idx = tid + l * 256;            // 0..2047 half8 chunks
    int n = idx >> 4, k8 = (idx & 15) << 3;
    *(half8*)&Ws[n][k8] = *(const half8*)(WhT + n * CH + k8);
  }
}

__device__ __forceinline__ void gemm_tile(
    const _Float16 (*Ws)[136], const half8* af,
    const float* __restrict__ dinv, unsigned char* __restrict__ C,
    int tile, int M, int quad, int sub) {
  f32x4 acc[8];
  #pragma unroll
  for (int j = 0; j < 8; ++j) acc[j] = (f32x4){0.f, 0.f, 0.f, 0.f};
  #pragma unroll
  for (int kc = 0; kc < 4; ++kc) {
    #pragma unroll
    for (int nt = 0; nt < 8; ++nt) {
      half8 b = *(const half8*)&Ws[nt * 16 + sub][kc * 32 + quad * 8];
      acc[nt] = __builtin_amdgcn_mfma_f32_16x16x32_f16(af[kc], b, acc[nt], 0, 0, 0);
    }
  }
  #pragma unroll
  for (int r = 0; r < 4; ++r) {
    int orow = tile * 16 + quad * 4 + r;
    if (orow < M) {
      float d = dinv[orow] * FP8_SCALE;
      #pragma unroll
      for (int nt = 0; nt < 8; ++nt)
        C[(size_t)orow * CH + nt * 16 + sub] = enc8(acc[nt][r] * d);
    }
  }
}

// A input fp32 (layer 1: x)
__global__ __launch_bounds__(256) void k_gemm_f32(
    const float* __restrict__ A, const _Float16* __restrict__ WhT,
    const float* __restrict__ dinv, unsigned char* __restrict__ C, int M) {
  __shared__ _Float16 Ws[128][136];
  int tid = threadIdx.x;
  stage_w(WhT, Ws, tid);
  __syncthreads();
  int lane = tid & 63;
  int quad = lane >> 4, sub = lane & 15;
  int ntiles = (M + 15) >> 4;
  int wid0 = blockIdx.x * 4 + (tid >> 6);
  int wstep = gridDim.x * 4;
  for (int tile = wid0; tile < ntiles; tile += wstep) {
    int row = tile * 16 + sub; if (row >= M) row = M - 1;
    const float* arow = A + (size_t)row * CH + quad * 8;
    half8 af[4];
    #pragma unroll
    for (int kc = 0; kc < 4; ++kc) {
      float4 v0 = *(const float4*)(arow + kc * 32);
      float4 v1 = *(const float4*)(arow + kc * 32 + 4);
      af[kc] = (half8){(_Float16)v0.x, (_Float16)v0.y, (_Float16)v0.z, (_Float16)v0.w,
                       (_Float16)v1.x, (_Float16)v1.y, (_Float16)v1.z, (_Float16)v1.w};
    }
    gemm_tile(Ws, af, dinv, C, tile, M, quad, sub);
  }
}

// A input fp16 (layer 2: h)
__global__ __launch_bounds__(256) void k_gemm_f16(
    const _Float16* __restrict__ A, const _Float16* __restrict__ WhT,
    const float* __restrict__ dinv, unsigned char* __restrict__ C, int M) {
  __shared__ _Float16 Ws[128][136];
  int tid = threadIdx.x;
  stage_w(WhT, Ws, tid);
  __syncthreads();
  int lane = tid & 63;
  int quad = lane >> 4, sub = lane & 15;
  int ntiles = (M + 15) >> 4;
  int wid0 = blockIdx.x * 4 + (tid >> 6);
  int wstep = gridDim.x * 4;
  for (int tile = wid0; tile < ntiles; tile += wstep) {
    int row = tile * 16 + sub; if (row >= M) row = M - 1;
    const _Float16* arow = A + (size_t)row * CH + quad * 8;
    half8 af[4];
    #pragma unroll
    for (int kc = 0; kc < 4; ++kc)
      af[kc] = *(const half8*)(arow + kc * 32);
    gemm_tile(Ws, af, dinv, C, tile, M, quad, sub);
  }
}

// ---------------------------------------------------------------------------
// Aggregation (pull, CSR): R6/R7 full-range structure (at the request-rate
// wall). 2 edge-rows per dword instruction, 2-node lockstep, csr prefetch,
// shfl_xor(32) fold.
// ---------------------------------------------------------------------------
__global__ __launch_bounds__(256) void k_agg(
    const unsigned int* __restrict__ xs32, const int* __restrict__ csr,
    const int* __restrict__ offs, const int* __restrict__ oend,
    const float* __restrict__ dinv, const float* __restrict__ bias,
    __half* __restrict__ out, int N) {
  int lane  = threadIdx.x & 63;
  int wid0  = blockIdx.x * 4 + (threadIdx.x >> 6);
  int wstep = gridDim.x * 4;
  int e = lane >> 5;                    // edge slot within pair
  unsigned int c = lane & 31;           // dword index within row
  float4 bb = *(const float4*)(bias + c * 4);

  auto G = [&](int s) -> unsigned int {
    return xs32[((unsigned int)s << 5) | c];
  };

  for (int wid = wid0; wid * 2 < N; wid += wstep) {
    int nA = wid * 2, nB = nA + 1;
    bool hasB = (nB < N);

    int eA = offs[nA];
    int cA = (oend[nA] - eA + 3) >> 2;                 // int4 chunk count
    int eB = hasB ? offs[nB] : eA;
    int cB = hasB ? ((oend[nB] - eB + 3) >> 2) : 0;

    f32x2 a0 = {0.f, 0.f}, a1 = {0.f, 0.f};
    f32x2 b0 = {0.f, 0.f}, b1 = {0.f, 0.f};
    if (e == 0) {                        // self row, counted once
      unsigned int ow = G(nA);
      a0 = __builtin_amdgcn_cvt_pk_f32_fp8((int)ow, false);
      a1 = __builtin_amdgcn_cvt_pk_f32_fp8((int)ow, true);
      if (hasB) {
        unsigned int ob = G(nB);
        b0 = __builtin_amdgcn_cvt_pk_f32_fp8((int)ob, false);
        b1 = __builtin_amdgcn_cvt_pk_f32_fp8((int)ob, true);
      }
    }

    #define ACC(d, x0, x1) \
      x0 += __builtin_amdgcn_cvt_pk_f32_fp8((int)(d), false); \
      x1 += __builtin_amdgcn_cvt_pk_f32_fp8((int)(d), true);

    if (cA >= 2 && cB >= 2) {
      int4 ca0 = *(const int4*)(csr + eA);
      int4 ca1 = *(const int4*)(csr + eA + 4);
      int4 cb0 = *(const int4*)(csr + eB);
      int4 cb1 = *(const int4*)(csr + eB + 4);
      do {
        int sA0 = e ? ca0.y : ca0.x, sA1 = e ? ca0.w : ca0.z;
        int sA2 = e ? ca1.y : ca1.x, sA3 = e ? ca1.w : ca1.z;
        int sB0 = e ? cb0.y : cb0.x, sB1 = e ? cb0.w : cb0.z;
        int sB2 = e ? cb1.y : cb1.x, sB3 = e ? cb1.w : cb1.z;
        unsigned int dA0 = G(sA0), dA1 = G(sA1), dA2 = G(sA2), dA3 = G(sA3);
        unsigned int dB0 = G(sB0), dB1 = G(sB1), dB2 = G(sB2), dB3 = G(sB3);
        eA += 8; eB += 8; cA -= 2; cB -= 2;
        int4 na0 = *(const int4*)(csr + eA);
        int4 na1 = *(const int4*)(csr + eA + 4);
        int4 nb0 = *(const int4*)(csr + eB);
        int4 nb1 = *(const int4*)(csr + eB + 4);
        ACC(dA0, a0, a1); ACC(dA1, a0, a1); ACC(dA2, a0, a1); ACC(dA3, a0, a1);
        ACC(dB0, b0, b1); ACC(dB1, b0, b1); ACC(dB2, b0, b1); ACC(dB3, b0, b1);
        ca0 = na0; ca1 = na1; cb0 = nb0; cb1 = nb1;
      } while (cA >= 2 && cB >= 2);
    }

    auto drain = [&](int ee, int cc, f32x2& x0, f32x2& x1) {
      while (cc >= 2) {
        int4 q0 = *(const int4*)(csr + ee);
        int4 q1 = *(const int4*)(csr + ee + 4);
        int s0 = e ? q0.y : q0.x, s1 = e ? q0.w : q0.z;
        int s2 = e ? q1.y : q1.x, s3 = e ? q1.w : q1.z;
        unsigned int d0 = G(s0), d1 = G(s1), d2 = G(s2), d3 = G(s3);
        ACC(d0, x0, x1); ACC(d1, x0, x1); ACC(d2, x0, x1); ACC(d3, x0, x1);
        ee += 8; cc -= 2;
      }
      if (cc > 0) {
        int4 q0 = *(const int4*)(csr + ee);
        int s0 = e ? q0.y : q0.x, s1 = e ? q0.w : q0.z;
        unsigned int d0 = G(s0), d1 = G(s1);
        ACC(d0, x0, x1); ACC(d1, x0, x1);
      }
    };
    drain(eA, cA, a0, a1);
    if (hasB) drain(eB, cB, b0, b1);
    #undef ACC

    a0[0] += __shfl_xor(a0[0], 32); a0[1] += __shfl_xor(a0[1], 32);
    a1[0] += __shfl_xor(a1[0], 32); a1[1] += __shfl_xor(a1[1], 32);
    if (hasB) {
      b0[0] += __shfl_xor(b0[0], 32); b0[1] += __shfl_xor(b0[1], 32);
      b1[0] += __shfl_xor(b1[0], 32); b1[1] += __shfl_xor(b1[1], 32);
    }

    if (e == 0) {
      {
        float dn = dinv[nA] * FP8_INV;
        float r0 = fmaf(a0[0], dn, bb.x), r1 = fmaf(a0[1], dn, bb.y);
        float r2 = fmaf(a1[0], dn, bb.z), r3 = fmaf(a1[1], dn, bb.w);
        __half2 h0 = __floats2half2_rn(fmaxf(r0, 0.f), fmaxf(r1, 0.f));
        __half2 h1 = __floats2half2_rn(fmaxf(r2, 0.f), fmaxf(r3, 0.f));
        __half2* op = (__half2*)(out + (size_t)nA * CH + c * 4);
        op[0] = h0; op[1] = h1;
      }
      if (hasB) {
        float dn = dinv[nB] * FP8_INV;
        float r0 = fmaf(b0[0], dn, bb.x), r1 = fmaf(b0[1], dn, bb.y);
        float r2 = fmaf(b1[0], dn, bb.z), r3 = fmaf(b1[1], dn, bb.w);
        __half2 h0 = __floats2half2_rn(fmaxf(r0, 0.f), fmaxf(r1, 0.f));
        __half2 h1 = __floats2half2_rn(fmaxf(r2, 0.f), fmaxf(r3, 0.f));
        __half2* op = (__half2*)(out + (size_t)nB * CH + c * 4);
        op[0] = h0; op[1] = h1;
      }
    }
  }
}

// ---------------------------------------------------------------------------
// Pool: 64-node block ranges (1563 blocks, 32 waves/CU -> TLP), 4-way row
// stride per channel-pair thread, unroll-4 for MLP. Partial per-graph runs
// flushed by atomicAdd (gsum pre-zeroed). Fixes R8's diagnosed 42us
// serial-latency-bound fused poolfc (1 block/graph, no unroll).
// ---------------------------------------------------------------------------
__global__ __launch_bounds__(256) void k_pool(
    const __half* __restrict__ h, const int* __restrict__ batch,
    float* __restrict__ gsum, int N) {
  int t = threadIdx.x;
  int ch2 = t & 63;          // half2 index (channels 2*ch2, 2*ch2+1)
  int rh  = t >> 6;          // 0..3 row offset
  int n0 = blockIdx.x * 64;
  int n1 = n0 + 64; if (n1 > N) n1 = N;
  int n = n0 + rh;
  if (n >= n1) return;
  const __half2* h2 = (const __half2*)h;
  int curg = batch[n];
  float ax = 0.f, ay = 0.f;
  #pragma unroll 4
  for (; n < n1; n += 4) {
    int g = batch[n];
    float2 v = __half22float2(h2[(size_t)n * 64 + ch2]);
    if (g != curg) {
      atomicAdd(&gsum[curg * CH + 2 * ch2], ax);
      atomicAdd(&gsum[curg * CH + 2 * ch2 + 1], ay);
      ax = 0.f; ay = 0.f; curg = g;
    }
    ax += v.x; ay += v.y;
  }
  atomicAdd(&gsum[curg * CH + 2 * ch2], ax);
  atomicAdd(&gsum[curg * CH + 2 * ch2 + 1], ay);
}

// ---------------------------------------------------------------------------
// FC: one block per graph, 8-way channel split (16 fmas/thread, fully
// unrolled -> all loads in flight), LDS reduce. Boundaries come precomputed
// from k_scatter's side job (no binary search).
// ---------------------------------------------------------------------------
__global__ __launch_bounds__(256) void k_fc(
    const float* __restrict__ gsum, const int* __restrict__ gstart,
    const int* __restrict__ gend, const float* __restrict__ Wfc,
    const float* __restrict__ bfc, float* __restrict__ outp) {
  __shared__ float part[8][NCLS];
  int g = blockIdx.x;
  int t = threadIdx.x;
  int j = t & 31, seg = t >> 5;
  float acc = 0.f;
  #pragma unroll
  for (int k = 0; k < 16; ++k) {
    int cc = seg * 16 + k;
    acc = fmaf(gsum[g * CH + cc], Wfc[cc * NCLS + j], acc);
  }
  part[seg][j] = acc;
  __syncthreads();
  if (t < NCLS) {
    float s = part[0][t] + part[1][t] + part[2][t] + part[3][t]
            + part[4][t] + part[5][t] + part[6][t] + part[7][t];
    int cnt = gend[g] - gstart[g];
    float invc = 1.0f / fmaxf((float)cnt, 1.0f);
    outp[g * NCLS + t] = fmaf(s, invc, bfc[t]);
  }
}

// ---------------------------------------------------------------------------
extern "C" void kernel_launch(void* const* d_in, const int* in_sizes, int n_in,
                              void* d_out, int out_size, void* d_ws, size_t ws_size,
                              hipStream_t stream) {
  const float* x    = (const float*)d_in[0];
  const int*   ei   = (const int*)d_in[1];
  const int*   batch= (const int*)d_in[2];
  const float* W1   = (const float*)d_in[3];
  const float* b1   = (const float*)d_in[4];
  const float* W2   = (const float*)d_in[5];
  const float* b2   = (const float*)d_in[6];
  const float* Wfc  = (const float*)d_in[7];
  const float* bfc  = (const float*)d_in[8];
  float* outp = (float*)d_out;

  const int N = in_sizes[0] / CH;       // 100000
  const int E = in_sizes[1] / 2;        // 3200000
  const int* src = ei;
  const int* dst = ei + E;
  const int NBUCK = (N + BW - 1) >> BSHIFT;   // 391
  int CAP = (E / NBUCK) + (E / NBUCK) / 8 + 1280;
  CAP = (CAP + 3) & ~3;                       // keep per-bucket base 4-aligned

  // Workspace carve (256B aligned). gcur+gsum adjacent -> ONE memset.
  char* w = (char*)d_ws;
  size_t o = 0;
  auto carve = [&](size_t bytes) -> void* {
    o = (o + 255) & ~(size_t)255;
    void* p = w + o;
    o += bytes;
    return p;
  };
  int*      gcur   = (int*)     carve(MAXB * 4);                 // zeroed
  float*    gsum   = (float*)   carve((size_t)NGRAPH * CH * 4);  // zeroed
  size_t zbytes = o;
  int*      gstart = (int*)     carve((size_t)NGRAPH * 4);
  int*      gend   = (int*)     carve((size_t)NGRAPH * 4);
  int*      offs   = (int*)     carve((size_t)N * 4);
  int*      oendb  = (int*)     carve((size_t)N * 4);
  int*      csr    = (int*)     carve((size_t)NBUCK * CAP * 4);
  float*    dinv   = (float*)   carve((size_t)N * 4);
  _Float16* WhT1   = (_Float16*)carve((size_t)CH * CH * 2);
  _Float16* WhT2   = (_Float16*)carve((size_t)CH * CH * 2);
  unsigned char* xsbuf = (unsigned char*)carve((size_t)(N + 1) * CH); // fp8 + zero row
  __half*   hbuf   = (__half*)  carve((size_t)N * CH * 2);            // fp16 h
  (void)ws_size;

  // ebuf (packed edges, gapped) aliases hbuf: NBUCK*CAP*4 ~ 16.4MB <= 25.6MB
  int* ebuf = (int*)hbuf;

  (void)hipMemsetAsync(gcur, 0, zbytes, stream);

  const int GBW = 1024;                 // waveGemm blocks (4/CU)
  const int PB  = (N + 63) / 64;        // pool blocks
  int AB = (N + 7) / 8;
  if (AB > 2048) AB = 2048;

  k_scatter<<<(E + 8191) / 8192, 1024, 0, stream>>>(
      src, dst, gcur, ebuf, E, CAP, (int*)(xsbuf + (size_t)N * CH),
      batch, gstart, gend, N);
  k_build<<<NBUCK, 1024, 0, stream>>>(ebuf, gcur, offs, oendb, dinv, csr,
                                      N, CAP, W1, W2, WhT1, WhT2);

  // Layer 1: xs = fp8((x@W1)*dinv*64) ; h = fp16(relu(agg(xs)*dinv/64 + b1))
  k_gemm_f32<<<GBW, 256, 0, stream>>>(x, WhT1, dinv, xsbuf, N);
  k_agg<<<AB, 256, 0, stream>>>((const unsigned int*)xsbuf, csr, offs, oendb,
                                dinv, b1, hbuf, N);
  // Layer 2
  k_gemm_f16<<<GBW, 256, 0, stream>>>((const _Float16*)hbuf, WhT2, dinv, xsbuf, N);
  k_agg<<<AB, 256, 0, stream>>>((const unsigned int*)xsbuf, csr, offs, oendb,
                                dinv, b2, hbuf, N);

  // Pool + FC
  k_pool<<<PB, 256, 0, stream>>>(hbuf, batch, gsum, N);
  k_fc<<<NGRAPH, 256, 0, stream>>>(gsum, gstart, gend, Wfc, bfc, outp);
  (void)out_size; (void)n_in;
}